// Round 1
// baseline (88.648 us; speedup 1.0000x reference)
//
#include <hip/hip_runtime.h>

// Problem constants (B=1, C=1, H=W=96)
#define NPTS 9216          // 96*96
#define WIDTH 96
#define TILE 256           // points per block / per j-tile
#define NTILES 36          // 9216 / 256

// Kernel 1: pack per-point features into ws and zero the output.
// Record layout (8 floats, 32 B): [x/15, y/15, 8r, 8g, 8b, (1-s), s, 0]
__global__ __launch_bounds__(256)
void crf_feat_kernel(const float* __restrict__ s,
                     const float* __restrict__ img,
                     float* __restrict__ feat,
                     float* __restrict__ out) {
    int p = blockIdx.x * 256 + threadIdx.x;
    if (p == 0) out[0] = 0.0f;           // re-zero every launch (harness poisons d_out)
    if (p >= NPTS) return;
    int y = p / WIDTH;
    int x = p - y * WIDTH;
    float sv = s[p];
    float4 a, b;
    a.x = (float)x * (1.0f / 15.0f);
    a.y = (float)y * (1.0f / 15.0f);
    a.z = img[p]          * 8.0f;        // r / 0.125
    a.w = img[NPTS + p]   * 8.0f;        // g / 0.125
    b.x = img[2*NPTS + p] * 8.0f;        // b / 0.125
    b.y = 1.0f - sv;
    b.z = sv;
    b.w = 0.0f;
    float4* f4 = (float4*)feat;
    f4[2*p]     = a;
    f4[2*p + 1] = b;
}

// Kernel 2: one block = (i-tile, j-tile) pair of 256 points each.
// Thread t owns i = ibase+t, loops over 256 staged j's in LDS (broadcast reads).
__global__ __launch_bounds__(256)
void crf_pair_kernel(const float* __restrict__ feat,
                     float* __restrict__ out) {
    __shared__ float sh[TILE * 8];
    __shared__ float wavesum[4];

    const int tid = threadIdx.x;
    const int i = blockIdx.x * TILE + tid;
    const int jbase = blockIdx.y * TILE;

    // Stage j-tile: 256 threads x 32 B = 8 KB, fully coalesced float4 loads.
    const float4* f4 = (const float4*)feat;
    float4 ja = f4[2*(jbase + tid)];
    float4 jb = f4[2*(jbase + tid) + 1];
    ((float4*)sh)[2*tid]     = ja;
    ((float4*)sh)[2*tid + 1] = jb;

    // My i-point features (from global; L2-resident, 295 KB total).
    float4 fa = f4[2*i];
    float4 fb = f4[2*i + 1];
    const float si = fb.z;

    __syncthreads();

    float acc = 0.0f;
    #pragma unroll 8
    for (int j = 0; j < TILE; ++j) {
        const float* p = &sh[8*j];
        float dx = fa.x - p[0];
        float dy = fa.y - p[1];
        float dr = fa.z - p[2];
        float dg = fa.w - p[3];
        float db = fb.x - p[4];
        float d2 = dx*dx;
        d2 = fmaf(dy, dy, d2);
        d2 = fmaf(dr, dr, d2);
        d2 = fmaf(dg, dg, d2);
        d2 = fmaf(db, db, d2);
        float w = __expf(-0.5f * d2);    // v_exp_f32 path
        acc = fmaf(w, p[5], acc);        // * (1 - s_j)
    }
    acc *= si;

    // Wave (64-lane) shuffle reduction, then cross-wave via LDS.
    #pragma unroll
    for (int off = 32; off > 0; off >>= 1)
        acc += __shfl_down(acc, off, 64);
    if ((tid & 63) == 0) wavesum[tid >> 6] = acc;
    __syncthreads();
    if (tid == 0) {
        float t = wavesum[0] + wavesum[1] + wavesum[2] + wavesum[3];
        atomicAdd(out, t * (1.0f / (float)NPTS));
    }
}

extern "C" void kernel_launch(void* const* d_in, const int* in_sizes, int n_in,
                              void* d_out, int out_size, void* d_ws, size_t ws_size,
                              hipStream_t stream) {
    const float* s   = (const float*)d_in[0];   // [1,1,96,96] probs
    const float* img = (const float*)d_in[1];   // [1,3,96,96] rgb
    float* out  = (float*)d_out;                // scalar loss
    float* feat = (float*)d_ws;                 // NPTS * 8 floats = 295 KB

    crf_feat_kernel<<<NTILES, 256, 0, stream>>>(s, img, feat, out);
    dim3 grid(NTILES, NTILES);
    crf_pair_kernel<<<grid, 256, 0, stream>>>(feat, out);
}

// Round 2
// 78.126 us; speedup vs baseline: 1.1347x; 1.1347x over previous
//
#include <hip/hip_runtime.h>

// Problem constants (B=1, C=1, H=W=96)
#define NPTS  9216
#define WIDTH 96
#define IPT   4            // i-points per thread
#define IBLK  (256*IPT)    // 1024 i per block
#define NIB   9            // 9216/1024 i-blocks
#define JTILE 128
#define NJB   72           // 9216/128 j-blocks

// Prescale features by sqrt(log2(e)) so exp(-0.5 d2) == exp2(hs_i + hsl_j + dot)
#define KSCALE 1.2011224087864498f   // sqrt(1.4426950408889634)

typedef _Float16 half2v __attribute__((ext_vector_type(2)));
union H2F { half2v h; float f; };

// Kernel 1: build packed per-point records.
//  arrJ[p] = { h2(x,y), h2(r,g), h2(b,0), hsl = -0.5|f|^2*log2e + log2(1-s) }
//  arrI[p] = { h2(x,y), h2(r,g), h2(b,0), hs  = -0.5|f|^2*log2e }
// |f|^2 is computed from the fp16-ROUNDED features so e_ii is exact.
__global__ __launch_bounds__(256)
void crf_feat_kernel(const float* __restrict__ s,
                     const float* __restrict__ img,
                     float4* __restrict__ arrJ,
                     float4* __restrict__ arrI,
                     float* __restrict__ out) {
    int p = blockIdx.x * 256 + threadIdx.x;
    if (p == 0) out[0] = 0.0f;            // harness re-poisons d_out every launch
    if (p >= NPTS) return;
    int y = p / WIDTH;
    int x = p - y * WIDTH;
    float sv = s[p];
    float xs = (float)x * (KSCALE / 15.0f);
    float ys = (float)y * (KSCALE / 15.0f);
    float rs = img[p]          * (8.0f * KSCALE);
    float gs = img[NPTS + p]   * (8.0f * KSCALE);
    float bs = img[2*NPTS + p] * (8.0f * KSCALE);
    _Float16 xh = (_Float16)xs, yh = (_Float16)ys;
    _Float16 rh = (_Float16)rs, gh = (_Float16)gs, bh = (_Float16)bs;
    float xr = (float)xh, yr = (float)yh, rr = (float)rh, gr = (float)gh, br = (float)bh;
    float hs = -0.5f * (xr*xr + yr*yr + rr*rr + gr*gr + br*br);
    float hsl = hs + __builtin_amdgcn_logf(1.0f - sv);   // v_log_f32 = log2

    H2F xy; xy.h = half2v{xh, yh};
    H2F rg; rg.h = half2v{rh, gh};
    H2F b0; b0.h = half2v{bh, (_Float16)0.0f};

    float4 rj, ri;
    rj.x = xy.f; rj.y = rg.f; rj.z = b0.f; rj.w = hsl;
    ri.x = xy.f; ri.y = rg.f; ri.z = b0.f; ri.w = hs;
    arrJ[p] = rj;
    arrI[p] = ri;
}

// Kernel 2: grid (9 i-blocks, 72 j-tiles). Each thread owns IPT=4 i-points,
// loops over a 128-point j-tile staged in LDS (one ds_read_b128 per j,
// broadcast -> conflict-free). Per (i,j): add + 3x v_dot2_f32_f16 + exp2 + add.
__global__ __launch_bounds__(256)
void crf_pair_kernel(const float4* __restrict__ arrJ,
                     const float4* __restrict__ arrI,
                     const float* __restrict__ s,
                     float* __restrict__ out) {
    __shared__ float4 shJ[JTILE];
    __shared__ float wavesum[4];

    const int tid   = threadIdx.x;
    const int ibase = blockIdx.x * IBLK;
    const int jbase = blockIdx.y * JTILE;

    if (tid < JTILE) shJ[tid] = arrJ[jbase + tid];

    half2v xyi[IPT], rgi[IPT], b0i[IPT];
    float  hsi[IPT], svi[IPT];
    #pragma unroll
    for (int k = 0; k < IPT; ++k) {
        int i = ibase + k * 256 + tid;
        float4 r = arrI[i];
        H2F a; a.f = r.x; xyi[k] = a.h;
        H2F b; b.f = r.y; rgi[k] = b.h;
        H2F c; c.f = r.z; b0i[k] = c.h;
        hsi[k] = r.w;
        svi[k] = s[i];
    }

    __syncthreads();

    float acc[IPT];
    #pragma unroll
    for (int k = 0; k < IPT; ++k) acc[k] = 0.0f;

    #pragma unroll 4
    for (int j = 0; j < JTILE; ++j) {
        float4 rj = shJ[j];
        H2F a; a.f = rj.x;
        H2F b; b.f = rj.y;
        H2F c; c.f = rj.z;
        const half2v xyj = a.h, rgj = b.h, b0j = c.h;
        const float hslj = rj.w;
        #pragma unroll
        for (int k = 0; k < IPT; ++k) {
            float e = hsi[k] + hslj;
            e = __builtin_amdgcn_fdot2(xyi[k], xyj, e, false);
            e = __builtin_amdgcn_fdot2(rgi[k], rgj, e, false);
            e = __builtin_amdgcn_fdot2(b0i[k], b0j, e, false);
            acc[k] += __builtin_amdgcn_exp2f(e);
        }
    }

    float t = acc[0]*svi[0] + acc[1]*svi[1] + acc[2]*svi[2] + acc[3]*svi[3];

    #pragma unroll
    for (int off = 32; off > 0; off >>= 1)
        t += __shfl_down(t, off, 64);
    if ((tid & 63) == 0) wavesum[tid >> 6] = t;
    __syncthreads();
    if (tid == 0) {
        float r = wavesum[0] + wavesum[1] + wavesum[2] + wavesum[3];
        atomicAdd(out, r * (1.0f / (float)NPTS));
    }
}

extern "C" void kernel_launch(void* const* d_in, const int* in_sizes, int n_in,
                              void* d_out, int out_size, void* d_ws, size_t ws_size,
                              hipStream_t stream) {
    const float* s   = (const float*)d_in[0];   // [1,1,96,96] probs
    const float* img = (const float*)d_in[1];   // [1,3,96,96] rgb
    float* out = (float*)d_out;

    float4* arrJ = (float4*)d_ws;               // 9216 * 16 B
    float4* arrI = arrJ + NPTS;                 // 9216 * 16 B

    crf_feat_kernel<<<NPTS/256, 256, 0, stream>>>(s, img, arrJ, arrI, out);
    dim3 grid(NIB, NJB);
    crf_pair_kernel<<<grid, 256, 0, stream>>>(arrJ, arrI, s, out);
}